// Round 7
// baseline (563.232 us; speedup 1.0000x reference)
//
#include <hip/hip_runtime.h>
#include <hip/hip_bf16.h>
#include <cstddef>

#define BB 8
#define CC 512
#define NN 4096
#define CQ 64
#define MQ 64   // Q-rows per attn block
#define NJ 64   // j-tile

typedef short bf16x8 __attribute__((ext_vector_type(8)));
typedef float f32x4  __attribute__((ext_vector_type(4)));

// fp32 -> bf16 bits, round-to-nearest-even
static __device__ __forceinline__ unsigned bf16_bits(float f){
  unsigned u = __float_as_uint(f);
  u += 0x7fffu + ((u >> 16) & 1u);
  return u >> 16;
}
static __device__ __forceinline__ unsigned pack2bf(float lo, float hi){
  return bf16_bits(lo) | (bf16_bits(hi) << 16);
}

// ---- weights fp32 -> bf16 (Wqk packed: rows 0..63 = Wq, 64..127 = Wk) ----
__global__ __launch_bounds__(256) void cvt_w_kernel(
    const float* __restrict__ Wq, const float* __restrict__ Wk,
    const float* __restrict__ Wv,
    short* __restrict__ Wqkbf, short* __restrict__ Wvbf){
  const int i = blockIdx.x*256 + threadIdx.x;
  if (i < CQ*CC){
    Wqkbf[i]         = (short)bf16_bits(Wq[i]);
    Wqkbf[CQ*CC + i] = (short)bf16_bits(Wk[i]);
  }
  Wvbf[i] = (short)bf16_bits(Wv[i]);
}

// ---- x fp32 [b][c][n] -> xT bf16 [b][n][c] via LDS 64x64 tile ----
// Reads vectorized: float4 per lane (4x fewer global load instructions).
__global__ __launch_bounds__(256) void cvt_x_kernel(
    const float* __restrict__ x, short* __restrict__ xT){
  __shared__ float lds[64*67];
  const int tid = threadIdx.x;
  const int n0 = blockIdx.x*64, c0 = blockIdx.y*64, b = blockIdx.z;
  const float* xp = x + ((size_t)b*CC + c0)*NN + n0;
  const int n4  = (tid & 15)*4;
  const int cl0 = tid >> 4;        // 0..15
#pragma unroll
  for (int i=0;i<4;++i){
    const int cl = cl0 + i*16;
    const float4 v = *(const float4*)(xp + (size_t)cl*NN + n4);
    lds[(n4+0)*67 + cl] = v.x;
    lds[(n4+1)*67 + cl] = v.y;
    lds[(n4+2)*67 + cl] = v.z;
    lds[(n4+3)*67 + cl] = v.w;
  }
  __syncthreads();
  short* xTp = xT + ((size_t)b*NN + n0)*CC + c0;
#pragma unroll
  for (int p=0;p<2;++p){
    const int nl2 = (tid>>3) + p*32;
    const int c8 = (tid&7)*8;
    const float* r = &lds[nl2*67 + c8];
    uint4 v;
    v.x = pack2bf(r[0], r[1]);
    v.y = pack2bf(r[2], r[3]);
    v.z = pack2bf(r[4], r[5]);
    v.w = pack2bf(r[6], r[7]);
    *(uint4*)&xTp[(size_t)nl2*CC + c8] = v;
  }
}

// ---- Q,K projection via MFMA: D[n][o] = xT . Wqk^T;  Qbf/Kbf layout [b][n][64] ----
// Q is pre-scaled by log2(e) so attn can use raw v_exp_f32 (2^x).
__global__ __launch_bounds__(256) void proj_qk_mfma(
    const short* __restrict__ xT, const short* __restrict__ Wqkbf,
    const float* __restrict__ bq, const float* __restrict__ bk,
    short* __restrict__ Qbf, short* __restrict__ Kbf){
  const int tid  = threadIdx.x;
  const int lane = tid & 63;
  const int w    = tid >> 6;
  const int iq   = lane & 15;
  const int q    = lane >> 4;
  const int b    = blockIdx.z;
  const int n0w  = blockIdx.x*128 + w*32;

  f32x4 acc[2][8];
#pragma unroll
  for (int ns=0;ns<2;++ns)
#pragma unroll
    for (int os=0;os<8;++os) acc[ns][os] = (f32x4){0.f,0.f,0.f,0.f};

  const short* Abase = xT + ((size_t)b*NN + n0w + iq)*CC + q*8;
  const short* Bbase = Wqkbf + (size_t)iq*CC + q*8;

  for (int ks=0; ks<16; ++ks){
    const int k = ks*32;
    bf16x8 af[2], bf[8];
#pragma unroll
    for (int ns=0;ns<2;++ns) af[ns] = *(const bf16x8*)(Abase + (size_t)ns*16*CC + k);
#pragma unroll
    for (int os=0;os<8;++os) bf[os] = *(const bf16x8*)(Bbase + (size_t)os*16*CC + k);
#pragma unroll
    for (int ns=0;ns<2;++ns)
#pragma unroll
      for (int os=0;os<8;++os)
        acc[ns][os] = __builtin_amdgcn_mfma_f32_16x16x32_bf16(af[ns], bf[os], acc[ns][os], 0,0,0);
  }
#pragma unroll
  for (int ns=0;ns<2;++ns){
#pragma unroll
    for (int os=0;os<8;++os){
      const int o = (os&4) ? ((os-4)*16 + iq) : (os*16 + iq);
      const float bias = (os<4) ? bq[o] : bk[o];
      short* dst = (os<4) ? Qbf : Kbf;
#pragma unroll
      for (int r=0;r<4;++r){
        const int n = n0w + ns*16 + q*4 + r;
        float v = acc[ns][os][r] + bias;
        if (os < 4) v *= 1.44269504088896f;  // fold log2(e) into Q
        dst[((size_t)b*NN + n)*CQ + o] = (short)bf16_bits(v);
      }
    }
  }
}

// ---- V projection via MFMA: D[c][n] = Wv . x;  Vbf layout [b][c][n] ----
// 64c x 64n per wave (acc[4][4]): 16 MFMA per 8 loads per ks.
__global__ __launch_bounds__(256) void proj_v_mfma(
    const short* __restrict__ xT, const short* __restrict__ Wvbf,
    const float* __restrict__ bv, short* __restrict__ Vbf){
  const int tid  = threadIdx.x;
  const int lane = tid & 63;
  const int w    = tid >> 6;
  const int iq   = lane & 15;
  const int q    = lane >> 4;
  const int b    = blockIdx.z;
  const int c0w  = blockIdx.y*128 + (w&1)*64;
  const int n0w  = blockIdx.x*128 + (w>>1)*64;

  f32x4 acc[4][4];   // [cs][ns]
#pragma unroll
  for (int cs=0;cs<4;++cs)
#pragma unroll
    for (int ns=0;ns<4;++ns) acc[cs][ns] = (f32x4){0.f,0.f,0.f,0.f};

  const short* Abase = Wvbf + (size_t)(c0w + iq)*CC + q*8;
  const short* Bbase = xT + ((size_t)b*NN + n0w + iq)*CC + q*8;

  for (int ks=0; ks<16; ++ks){
    const int k = ks*32;
    bf16x8 af[4], bf[4];
#pragma unroll
    for (int cs=0;cs<4;++cs) af[cs] = *(const bf16x8*)(Abase + (size_t)cs*16*CC + k);
#pragma unroll
    for (int ns=0;ns<4;++ns) bf[ns] = *(const bf16x8*)(Bbase + (size_t)ns*16*CC + k);
#pragma unroll
    for (int cs=0;cs<4;++cs)
#pragma unroll
      for (int ns=0;ns<4;++ns)
        acc[cs][ns] = __builtin_amdgcn_mfma_f32_16x16x32_bf16(af[cs], bf[ns], acc[cs][ns], 0,0,0);
  }
#pragma unroll
  for (int cs=0;cs<4;++cs){
#pragma unroll
    for (int r=0;r<4;++r){
      const int c = c0w + cs*16 + q*4 + r;
      const float bias = bv[c];
#pragma unroll
      for (int ns=0;ns<4;++ns){
        const int n = n0w + ns*16 + iq;
        Vbf[((size_t)b*CC + c)*NN + n] = (short)bf16_bits(acc[cs][ns][r] + bias);
      }
    }
  }
}

// ---- MFMA flash attention, 8-wave blocks (occupancy: total regs <= 128/wave) ----
// Grid 1024 x 512 threads: bid&7 = batch (XCD swizzle), (bid>>3)&1 = c-half (256 ch),
// bid>>4 = i-tile (64). SAME traffic/FLOPs/LDS layout as the 4-wave version; the
// per-wave tile is halved so acc=32 (+arch ~75) fits the <=128 total -> 16 waves/CU
// (m69 occupancy steps at 64/128/256: no 3-wave regime exists, so 172->128 is the
// only reachable occupancy improvement without traffic growth).
// QK role: wave w -> (jg = w>>1: 16 j-rows, ih = w&1: 32 i-rows), 4 MFMA/jt.
// PV role: wave w -> (cg = w: 32 channels, all 64 i), 16 MFMA/jt.
// P LDS exchange layout identical to the proven 4-wave scheme (woff/roff algebra).
__global__ __launch_bounds__(512, 2) void attn_mfma_kernel(
    const short* __restrict__ Qbf, const short* __restrict__ Kbf,
    const short* __restrict__ Vbf, const float* __restrict__ x,
    const float* __restrict__ gamma, float* __restrict__ out){
  __shared__ unsigned plds[2][2048];
  __shared__ float lsum[4][MQ];

  const int tid  = threadIdx.x;
  const int lane = tid & 63;
  const int w    = tid >> 6;        // 0..7
  const int iq   = lane & 15;
  const int q    = lane >> 4;
  const int bid  = blockIdx.x;
  const int b    = bid & 7;
  const int ch   = ((bid >> 3) & 1) * 256;
  const int i0   = (bid >> 4) * MQ;

  const int jg   = w >> 1;          // QK j-group (16 rows)
  const int ih   = w & 1;           // QK i-half (32 rows)
  const int cg   = w;               // PV c-group (32 channels)

  // Q B-frags: this wave's 32 i-rows (pre-scaled by log2e in proj)
  bf16x8 qb[2][2];
#pragma unroll
  for (int s=0;s<2;++s){
    const short* qp = Qbf + ((size_t)b*NN + i0 + ih*32 + s*16 + iq)*CQ + q*8;
    qb[s][0] = *(const bf16x8*)qp;
    qb[s][1] = *(const bf16x8*)(qp + 32);
  }

  f32x4 acc[2][4];   // [cs: 2 c-sixteens][s: 4 i-groups]
#pragma unroll
  for (int cs=0;cs<2;++cs)
#pragma unroll
    for (int s=0;s<4;++s) acc[cs][s] = (f32x4){0.f,0.f,0.f,0.f};
  float lpart[2] = {0.f,0.f};

  const short* Kbase = Kbf + ((size_t)b*NN + jg*16 + iq)*CQ + q*8;        // A[m=j][k=o]
  const short* Vbase = Vbf + ((size_t)b*CC + ch + cg*32 + iq)*NN + q*8;   // A[m=c][k=j]

  // LDS dword offsets. Writer (jg,ih): chunk jo=jg*2+(q>>1), i=ih*32+s*16+iq,
  //   dword = jo*256 + i*4 + (q&1)*2  ->  woff + s*64.
  // Reader: jo=q (+4 for kh=1), i=s*16+iq -> roff0 + s*64 (+1024).
  const int woff  = (jg*2 + (q>>1))*256 + ih*128 + iq*4 + (q&1)*2;
  const int roff0 = q*256 + iq*4;

  // K frags for jt=0 (single buffer; reloaded each jt after QK consumes them)
  bf16x8 ka0 = *(const bf16x8*)Kbase;
  bf16x8 ka1 = *(const bf16x8*)(Kbase + 32);

#pragma unroll 2
  for (int jt=0; jt<NN/NJ; ++jt){
    const int buf = jt & 1;
    const int j0 = jt*NJ;

    // ---- issue V loads for THIS jt (consumed after barrier; distance proven in r2) ----
    bf16x8 va[2][2];
    const short* vp = Vbase + j0;
#pragma unroll
    for (int cs=0;cs<2;++cs){
      const short* vrow = vp + (size_t)cs*16*NN;
      va[cs][0] = *(const bf16x8*)vrow;
      va[cs][1] = *(const bf16x8*)(vrow + 32);
    }

    // ---- S^T = K . Q^T (16j x 32i), exp per-s immediately ----
#pragma unroll
    for (int s=0;s<2;++s){
      f32x4 sfs;
      sfs = __builtin_amdgcn_mfma_f32_16x16x32_bf16(ka0, qb[s][0], (f32x4){0.f,0.f,0.f,0.f}, 0,0,0);
      sfs = __builtin_amdgcn_mfma_f32_16x16x32_bf16(ka1, qb[s][1], sfs, 0,0,0);
      const float p0 = __builtin_amdgcn_exp2f(sfs[0]);
      const float p1 = __builtin_amdgcn_exp2f(sfs[1]);
      const float p2 = __builtin_amdgcn_exp2f(sfs[2]);
      const float p3 = __builtin_amdgcn_exp2f(sfs[3]);
      lpart[s] += (p0+p1) + (p2+p3);
      uint2 pw;
      pw.x = pack2bf(p0, p1);
      pw.y = pack2bf(p2, p3);
      *(uint2*)&plds[buf][woff + s*64] = pw;   // ds_write_b64
    }

    // ---- reload K for jt+1 (used after barrier+PV; overread stays in workspace) ----
    {
      const short* kp = Kbase + (size_t)(j0 + NJ)*CQ;
      ka0 = *(const bf16x8*)kp;
      ka1 = *(const bf16x8*)(kp + 32);
    }

    // ---- LDS-only barrier: wait lgkmcnt(0), leave vmcnt in flight ----
    __builtin_amdgcn_s_waitcnt(0xc07f);
    __builtin_amdgcn_s_barrier();

    // ---- PV: 32c x 64i, B-frags from LDS, A = V issued this jt ----
#pragma unroll
    for (int s=0;s<4;++s){
      const bf16x8 pb0 = *(const bf16x8*)&plds[buf][roff0 + s*64];
      const bf16x8 pb1 = *(const bf16x8*)&plds[buf][roff0 + s*64 + 1024];
#pragma unroll
      for (int cs=0;cs<2;++cs){
        acc[cs][s] = __builtin_amdgcn_mfma_f32_16x16x32_bf16(va[cs][0], pb0, acc[cs][s], 0,0,0);
        acc[cs][s] = __builtin_amdgcn_mfma_f32_16x16x32_bf16(va[cs][1], pb1, acc[cs][s], 0,0,0);
      }
    }
  }

  // ---- l reduction: sum over q within wave, then across 4 jg via LDS ----
#pragma unroll
  for (int s=0;s<2;++s){
    lpart[s] += __shfl_xor(lpart[s], 16, 64);
    lpart[s] += __shfl_xor(lpart[s], 32, 64);
  }
  __syncthreads();
  if (q == 0){
#pragma unroll
    for (int s=0;s<2;++s) lsum[jg][ih*32 + s*16 + iq] = lpart[s];
  }
  __syncthreads();
  float linv[4];
#pragma unroll
  for (int s=0;s<4;++s){
    const int i = s*16 + iq;
    linv[s] = 1.0f / (lsum[0][i] + lsum[1][i] + lsum[2][i] + lsum[3][i]);
  }

  const float gam = gamma[0];
#pragma unroll
  for (int cs=0;cs<2;++cs){
#pragma unroll
    for (int s=0;s<4;++s){
      const int cb = ch + cg*32 + cs*16 + q*4;
      const int i  = i0 + s*16 + iq;
#pragma unroll
      for (int r=0;r<4;++r){
        const size_t idx = ((size_t)b*CC + cb + r)*NN + i;
        out[idx] = fmaf(gam, acc[cs][s][r]*linv[s], x[idx]);
      }
    }
  }
}

extern "C" void kernel_launch(void* const* d_in, const int* in_sizes, int n_in,
                              void* d_out, int out_size, void* d_ws, size_t ws_size,
                              hipStream_t stream){
  const float* x     = (const float*)d_in[0];
  const float* Wq    = (const float*)d_in[1];
  const float* bq    = (const float*)d_in[2];
  const float* Wk    = (const float*)d_in[3];
  const float* bk    = (const float*)d_in[4];
  const float* Wv    = (const float*)d_in[5];
  const float* bv    = (const float*)d_in[6];
  const float* gamma = (const float*)d_in[7];
  float* out = (float*)d_out;

  // workspace: xT bf16 [8][4096][512] 33.6MB; Qbf/Kbf bf16 [8][4096][64] 4.2MB each;
  // Vbf bf16 [8][512][4096] 33.6MB; Wqkbf [128][512] 128KB; Wvbf [512][512] 512KB. ~76 MB
  short* xTbf = (short*)d_ws;
  short* Qbf  = xTbf + (size_t)BB*NN*CC;
  short* Kbf  = Qbf  + (size_t)BB*NN*CQ;
  short* Vbf  = Kbf  + (size_t)BB*NN*CQ;
  short* Wqkbf= Vbf  + (size_t)BB*CC*NN;
  short* Wvbf = Wqkbf + (size_t)2*CQ*CC;

  cvt_w_kernel<<<dim3(CC*CC/256), 256, 0, stream>>>(Wq, Wk, Wv, Wqkbf, Wvbf);
  cvt_x_kernel<<<dim3(NN/64, CC/64, BB), 256, 0, stream>>>(x, xTbf);
  proj_qk_mfma<<<dim3(NN/128, 1, BB), 256, 0, stream>>>(xTbf, Wqkbf, bq, bk, Qbf, Kbf);
  proj_v_mfma<<<dim3(NN/128, CC/128, BB), 256, 0, stream>>>(xTbf, Wvbf, bv, Vbf);
  attn_mfma_kernel<<<dim3(BB*NN*2/MQ), 512, 0, stream>>>(Qbf, Kbf, Vbf, x, gamma, out);
}

// Round 8
// 512.778 us; speedup vs baseline: 1.0984x; 1.0984x over previous
//
#include <hip/hip_runtime.h>
#include <hip/hip_bf16.h>
#include <cstddef>

#define BB 8
#define CC 512
#define NN 4096
#define CQ 64
#define MQ 64    // Q-rows per attn block
#define NJ 128   // j-tile per barrier period (2 sub-tiles of 64)

typedef short bf16x8 __attribute__((ext_vector_type(8)));
typedef float f32x4  __attribute__((ext_vector_type(4)));

// fp32 -> bf16 bits, round-to-nearest-even
static __device__ __forceinline__ unsigned bf16_bits(float f){
  unsigned u = __float_as_uint(f);
  u += 0x7fffu + ((u >> 16) & 1u);
  return u >> 16;
}
static __device__ __forceinline__ unsigned pack2bf(float lo, float hi){
  return bf16_bits(lo) | (bf16_bits(hi) << 16);
}

// ---- weights fp32 -> bf16 (Wqk packed: rows 0..63 = Wq, 64..127 = Wk) ----
__global__ __launch_bounds__(256) void cvt_w_kernel(
    const float* __restrict__ Wq, const float* __restrict__ Wk,
    const float* __restrict__ Wv,
    short* __restrict__ Wqkbf, short* __restrict__ Wvbf){
  const int i = blockIdx.x*256 + threadIdx.x;
  if (i < CQ*CC){
    Wqkbf[i]         = (short)bf16_bits(Wq[i]);
    Wqkbf[CQ*CC + i] = (short)bf16_bits(Wk[i]);
  }
  Wvbf[i] = (short)bf16_bits(Wv[i]);
}

// ---- x fp32 [b][c][n] -> xT bf16 [b][n][c] via LDS 64x64 tile ----
// Reads vectorized: float4 per lane.
__global__ __launch_bounds__(256) void cvt_x_kernel(
    const float* __restrict__ x, short* __restrict__ xT){
  __shared__ float lds[64*67];
  const int tid = threadIdx.x;
  const int n0 = blockIdx.x*64, c0 = blockIdx.y*64, b = blockIdx.z;
  const float* xp = x + ((size_t)b*CC + c0)*NN + n0;
  const int n4  = (tid & 15)*4;
  const int cl0 = tid >> 4;        // 0..15
#pragma unroll
  for (int i=0;i<4;++i){
    const int cl = cl0 + i*16;
    const float4 v = *(const float4*)(xp + (size_t)cl*NN + n4);
    lds[(n4+0)*67 + cl] = v.x;
    lds[(n4+1)*67 + cl] = v.y;
    lds[(n4+2)*67 + cl] = v.z;
    lds[(n4+3)*67 + cl] = v.w;
  }
  __syncthreads();
  short* xTp = xT + ((size_t)b*NN + n0)*CC + c0;
#pragma unroll
  for (int p=0;p<2;++p){
    const int nl2 = (tid>>3) + p*32;
    const int c8 = (tid&7)*8;
    const float* r = &lds[nl2*67 + c8];
    uint4 v;
    v.x = pack2bf(r[0], r[1]);
    v.y = pack2bf(r[2], r[3]);
    v.z = pack2bf(r[4], r[5]);
    v.w = pack2bf(r[6], r[7]);
    *(uint4*)&xTp[(size_t)nl2*CC + c8] = v;
  }
}

// ---- Q,K projection via MFMA: D[n][o] = xT . Wqk^T;  Qbf/Kbf layout [b][n][64] ----
// Q is pre-scaled by log2(e) so attn can use raw v_exp_f32 (2^x).
__global__ __launch_bounds__(256) void proj_qk_mfma(
    const short* __restrict__ xT, const short* __restrict__ Wqkbf,
    const float* __restrict__ bq, const float* __restrict__ bk,
    short* __restrict__ Qbf, short* __restrict__ Kbf){
  const int tid  = threadIdx.x;
  const int lane = tid & 63;
  const int w    = tid >> 6;
  const int iq   = lane & 15;
  const int q    = lane >> 4;
  const int b    = blockIdx.z;
  const int n0w  = blockIdx.x*128 + w*32;

  f32x4 acc[2][8];
#pragma unroll
  for (int ns=0;ns<2;++ns)
#pragma unroll
    for (int os=0;os<8;++os) acc[ns][os] = (f32x4){0.f,0.f,0.f,0.f};

  const short* Abase = xT + ((size_t)b*NN + n0w + iq)*CC + q*8;
  const short* Bbase = Wqkbf + (size_t)iq*CC + q*8;

  for (int ks=0; ks<16; ++ks){
    const int k = ks*32;
    bf16x8 af[2], bf[8];
#pragma unroll
    for (int ns=0;ns<2;++ns) af[ns] = *(const bf16x8*)(Abase + (size_t)ns*16*CC + k);
#pragma unroll
    for (int os=0;os<8;++os) bf[os] = *(const bf16x8*)(Bbase + (size_t)os*16*CC + k);
#pragma unroll
    for (int ns=0;ns<2;++ns)
#pragma unroll
      for (int os=0;os<8;++os)
        acc[ns][os] = __builtin_amdgcn_mfma_f32_16x16x32_bf16(af[ns], bf[os], acc[ns][os], 0,0,0);
  }
#pragma unroll
  for (int ns=0;ns<2;++ns){
#pragma unroll
    for (int os=0;os<8;++os){
      const int o = (os&4) ? ((os-4)*16 + iq) : (os*16 + iq);
      const float bias = (os<4) ? bq[o] : bk[o];
      short* dst = (os<4) ? Qbf : Kbf;
#pragma unroll
      for (int r=0;r<4;++r){
        const int n = n0w + ns*16 + q*4 + r;
        float v = acc[ns][os][r] + bias;
        if (os < 4) v *= 1.44269504088896f;  // fold log2(e) into Q
        dst[((size_t)b*NN + n)*CQ + o] = (short)bf16_bits(v);
      }
    }
  }
}

// ---- V projection via MFMA: D[c][n] = Wv . x;  Vbf layout [b][c][n] ----
// 64c x 64n per wave (acc[4][4]): 16 MFMA per 8 loads per ks.
__global__ __launch_bounds__(256) void proj_v_mfma(
    const short* __restrict__ xT, const short* __restrict__ Wvbf,
    const float* __restrict__ bv, short* __restrict__ Vbf){
  const int tid  = threadIdx.x;
  const int lane = tid & 63;
  const int w    = tid >> 6;
  const int iq   = lane & 15;
  const int q    = lane >> 4;
  const int b    = blockIdx.z;
  const int c0w  = blockIdx.y*128 + (w&1)*64;
  const int n0w  = blockIdx.x*128 + (w>>1)*64;

  f32x4 acc[4][4];   // [cs][ns]
#pragma unroll
  for (int cs=0;cs<4;++cs)
#pragma unroll
    for (int ns=0;ns<4;++ns) acc[cs][ns] = (f32x4){0.f,0.f,0.f,0.f};

  const short* Abase = Wvbf + (size_t)(c0w + iq)*CC + q*8;
  const short* Bbase = xT + ((size_t)b*NN + n0w + iq)*CC + q*8;

  for (int ks=0; ks<16; ++ks){
    const int k = ks*32;
    bf16x8 af[4], bf[4];
#pragma unroll
    for (int cs=0;cs<4;++cs) af[cs] = *(const bf16x8*)(Abase + (size_t)cs*16*CC + k);
#pragma unroll
    for (int ns=0;ns<4;++ns) bf[ns] = *(const bf16x8*)(Bbase + (size_t)ns*16*CC + k);
#pragma unroll
    for (int cs=0;cs<4;++cs)
#pragma unroll
      for (int ns=0;ns<4;++ns)
        acc[cs][ns] = __builtin_amdgcn_mfma_f32_16x16x32_bf16(af[cs], bf[ns], acc[cs][ns], 0,0,0);
  }
#pragma unroll
  for (int cs=0;cs<4;++cs){
#pragma unroll
    for (int r=0;r<4;++r){
      const int c = c0w + cs*16 + q*4 + r;
      const float bias = bv[c];
#pragma unroll
      for (int ns=0;ns<4;++ns){
        const int n = n0w + ns*16 + iq;
        Vbf[((size_t)b*CC + c)*NN + n] = (short)bf16_bits(acc[cs][ns][r] + bias);
      }
    }
  }
}

// ---- MFMA flash attention, NJ=128: 32 barrier periods instead of 64 ----
// Grid 1024 x 256 thr: bid&7 = batch (XCD swizzle), (bid>>3)&1 = c-half, bid>>4 = i-tile.
// r7 falsified TLP-starvation (2x occupancy -> slower); r0/r2/r4/r6 all hit 330us ->
// the invariant is per-barrier-period overhead x 64. This kernel halves the period
// count: each period processes TWO 64-j sub-tiles (QK+exp+write x2, one barrier,
// PV x2). Same FLOPs, same j-accumulation order (bitwise-identical), LDS 33KB
// (2 bufs x 4096 dwords), live regs ~196 < 256 -> still 2 waves/SIMD, no spill.
__global__ __launch_bounds__(256, 2) void attn_mfma_kernel(
    const short* __restrict__ Qbf, const short* __restrict__ Kbf,
    const short* __restrict__ Vbf, const float* __restrict__ x,
    const float* __restrict__ gamma, float* __restrict__ out){
  __shared__ unsigned plds[2][4096];
  __shared__ float lsum[4][MQ];

  const int tid  = threadIdx.x;
  const int lane = tid & 63;
  const int w    = tid >> 6;
  const int iq   = lane & 15;
  const int q    = lane >> 4;
  const int bid  = blockIdx.x;
  const int b    = bid & 7;
  const int ch   = ((bid >> 3) & 1) * 256;
  const int i0   = (bid >> 4) * MQ;

  // Q B-frags (persistent), pre-scaled by log2(e) in proj
  bf16x8 qb[4][2];
#pragma unroll
  for (int s=0;s<4;++s){
    const short* qp = Qbf + ((size_t)b*NN + i0 + s*16 + iq)*CQ + q*8;
    qb[s][0] = *(const bf16x8*)qp;
    qb[s][1] = *(const bf16x8*)(qp + 32);
  }

  f32x4 acc[4][4];
#pragma unroll
  for (int cs=0;cs<4;++cs)
#pragma unroll
    for (int s=0;s<4;++s) acc[cs][s] = (f32x4){0.f,0.f,0.f,0.f};
  float lpart[4] = {0.f,0.f,0.f,0.f};

  const short* Kbase = Kbf + ((size_t)b*NN + w*16 + iq)*CQ + q*8;        // A[m=j][k=o]
  const short* Vbase = Vbf + ((size_t)b*CC + ch + w*64 + iq)*NN + q*8;   // A[m=c][k=j]

  // LDS dword offsets (per 64-j sub-tile; sub1 adds +2048):
  // writer chunk jo=w*2+(q>>1); reader jo=q (+4 via +1024)
  const int woff  = (w*2 + (q>>1))*256 + iq*4 + (q&1)*2;   // + s*64
  const int roff0 = q*256 + iq*4;                          // + s*64 (+1024)

  // K frags for jt=0, both sub-tiles (reloaded after consumption each period)
  bf16x8 kaA0 = *(const bf16x8*)Kbase;
  bf16x8 kaA1 = *(const bf16x8*)(Kbase + 32);
  bf16x8 kaB0 = *(const bf16x8*)(Kbase + (size_t)64*CQ);
  bf16x8 kaB1 = *(const bf16x8*)(Kbase + (size_t)64*CQ + 32);

#pragma unroll 2
  for (int jt=0; jt<NN/NJ; ++jt){
    const int buf = jt & 1;
    const int j0 = jt*NJ;

    // ---- V loads sub0 (consumed after barrier in PV sub0) ----
    bf16x8 va0[4][2];
    {
      const short* vp = Vbase + j0;
#pragma unroll
      for (int cs=0;cs<4;++cs){
        const short* vrow = vp + (size_t)cs*16*NN;
        va0[cs][0] = *(const bf16x8*)vrow;
        va0[cs][1] = *(const bf16x8*)(vrow + 32);
      }
    }

    // ---- QK sub0 + exp + LDS write (dwords 0..2047 of buf) ----
#pragma unroll
    for (int s=0;s<4;++s){
      f32x4 sfs;
      sfs = __builtin_amdgcn_mfma_f32_16x16x32_bf16(kaA0, qb[s][0], (f32x4){0.f,0.f,0.f,0.f}, 0,0,0);
      sfs = __builtin_amdgcn_mfma_f32_16x16x32_bf16(kaA1, qb[s][1], sfs, 0,0,0);
      const float p0 = __builtin_amdgcn_exp2f(sfs[0]);
      const float p1 = __builtin_amdgcn_exp2f(sfs[1]);
      const float p2 = __builtin_amdgcn_exp2f(sfs[2]);
      const float p3 = __builtin_amdgcn_exp2f(sfs[3]);
      lpart[s] += (p0+p1) + (p2+p3);
      uint2 pw;
      pw.x = pack2bf(p0, p1);
      pw.y = pack2bf(p2, p3);
      *(uint2*)&plds[buf][woff + s*64] = pw;
    }
    // reload kaA for jt+1 (overread past Kbf stays inside workspace, unused)
    {
      const short* kp = Kbase + (size_t)(j0 + NJ)*CQ;
      kaA0 = *(const bf16x8*)kp;
      kaA1 = *(const bf16x8*)(kp + 32);
    }

    // ---- V loads sub1 ----
    bf16x8 va1[4][2];
    {
      const short* vp = Vbase + j0 + 64;
#pragma unroll
      for (int cs=0;cs<4;++cs){
        const short* vrow = vp + (size_t)cs*16*NN;
        va1[cs][0] = *(const bf16x8*)vrow;
        va1[cs][1] = *(const bf16x8*)(vrow + 32);
      }
    }

    // ---- QK sub1 + exp + LDS write (dwords 2048..4095 of buf) ----
#pragma unroll
    for (int s=0;s<4;++s){
      f32x4 sfs;
      sfs = __builtin_amdgcn_mfma_f32_16x16x32_bf16(kaB0, qb[s][0], (f32x4){0.f,0.f,0.f,0.f}, 0,0,0);
      sfs = __builtin_amdgcn_mfma_f32_16x16x32_bf16(kaB1, qb[s][1], sfs, 0,0,0);
      const float p0 = __builtin_amdgcn_exp2f(sfs[0]);
      const float p1 = __builtin_amdgcn_exp2f(sfs[1]);
      const float p2 = __builtin_amdgcn_exp2f(sfs[2]);
      const float p3 = __builtin_amdgcn_exp2f(sfs[3]);
      lpart[s] += (p0+p1) + (p2+p3);
      uint2 pw;
      pw.x = pack2bf(p0, p1);
      pw.y = pack2bf(p2, p3);
      *(uint2*)&plds[buf][2048 + woff + s*64] = pw;
    }
    // reload kaB for jt+1
    {
      const short* kp = Kbase + (size_t)(j0 + NJ + 64)*CQ;
      kaB0 = *(const bf16x8*)kp;
      kaB1 = *(const bf16x8*)(kp + 32);
    }

    // ---- ONE lgkm-only barrier per 128-j period ----
    __builtin_amdgcn_s_waitcnt(0xc07f);
    __builtin_amdgcn_s_barrier();

    // ---- PV sub0 (j0..j0+63) ----
#pragma unroll
    for (int s=0;s<4;++s){
      const bf16x8 pb0 = *(const bf16x8*)&plds[buf][roff0 + s*64];
      const bf16x8 pb1 = *(const bf16x8*)&plds[buf][roff0 + s*64 + 1024];
#pragma unroll
      for (int cs=0;cs<4;++cs){
        acc[cs][s] = __builtin_amdgcn_mfma_f32_16x16x32_bf16(va0[cs][0], pb0, acc[cs][s], 0,0,0);
        acc[cs][s] = __builtin_amdgcn_mfma_f32_16x16x32_bf16(va0[cs][1], pb1, acc[cs][s], 0,0,0);
      }
    }
    // ---- PV sub1 (j0+64..j0+127) ----
#pragma unroll
    for (int s=0;s<4;++s){
      const bf16x8 pb0 = *(const bf16x8*)&plds[buf][2048 + roff0 + s*64];
      const bf16x8 pb1 = *(const bf16x8*)&plds[buf][2048 + roff0 + s*64 + 1024];
#pragma unroll
      for (int cs=0;cs<4;++cs){
        acc[cs][s] = __builtin_amdgcn_mfma_f32_16x16x32_bf16(va1[cs][0], pb0, acc[cs][s], 0,0,0);
        acc[cs][s] = __builtin_amdgcn_mfma_f32_16x16x32_bf16(va1[cs][1], pb1, acc[cs][s], 0,0,0);
      }
    }
  }

  // ---- l reduction ----
#pragma unroll
  for (int s=0;s<4;++s){
    lpart[s] += __shfl_xor(lpart[s], 16, 64);
    lpart[s] += __shfl_xor(lpart[s], 32, 64);
  }
  __syncthreads();
  if (q == 0){
#pragma unroll
    for (int s=0;s<4;++s) lsum[w][s*16 + iq] = lpart[s];
  }
  __syncthreads();
  float linv[4];
#pragma unroll
  for (int s=0;s<4;++s){
    const int i = s*16 + iq;
    linv[s] = 1.0f / (lsum[0][i] + lsum[1][i] + lsum[2][i] + lsum[3][i]);
  }

  const float gam = gamma[0];
#pragma unroll
  for (int cs=0;cs<4;++cs){
#pragma unroll
    for (int s=0;s<4;++s){
      const int cb = ch + w*64 + cs*16 + q*4;
      const int i  = i0 + s*16 + iq;
#pragma unroll
      for (int r=0;r<4;++r){
        const size_t idx = ((size_t)b*CC + cb + r)*NN + i;
        out[idx] = fmaf(gam, acc[cs][s][r]*linv[s], x[idx]);
      }
    }
  }
}

extern "C" void kernel_launch(void* const* d_in, const int* in_sizes, int n_in,
                              void* d_out, int out_size, void* d_ws, size_t ws_size,
                              hipStream_t stream){
  const float* x     = (const float*)d_in[0];
  const float* Wq    = (const float*)d_in[1];
  const float* bq    = (const float*)d_in[2];
  const float* Wk    = (const float*)d_in[3];
  const float* bk    = (const float*)d_in[4];
  const float* Wv    = (const float*)d_in[5];
  const float* bv    = (const float*)d_in[6];
  const float* gamma = (const float*)d_in[7];
  float* out = (float*)d_out;

  // workspace: xT bf16 [8][4096][512] 33.6MB; Qbf/Kbf bf16 [8][4096][64] 4.2MB each;
  // Vbf bf16 [8][512][4096] 33.6MB; Wqkbf [128][512] 128KB; Wvbf [512][512] 512KB. ~76 MB
  short* xTbf = (short*)d_ws;
  short* Qbf  = xTbf + (size_t)BB*NN*CC;
  short* Kbf  = Qbf  + (size_t)BB*NN*CQ;
  short* Vbf  = Kbf  + (size_t)BB*NN*CQ;
  short* Wqkbf= Vbf  + (size_t)BB*CC*NN;
  short* Wvbf = Wqkbf + (size_t)2*CQ*CC;

  cvt_w_kernel<<<dim3(CC*CC/256), 256, 0, stream>>>(Wq, Wk, Wv, Wqkbf, Wvbf);
  cvt_x_kernel<<<dim3(NN/64, CC/64, BB), 256, 0, stream>>>(x, xTbf);
  proj_qk_mfma<<<dim3(NN/128, 1, BB), 256, 0, stream>>>(xTbf, Wqkbf, bq, bk, Qbf, Kbf);
  proj_v_mfma<<<dim3(NN/128, CC/128, BB), 256, 0, stream>>>(xTbf, Wvbf, bv, Vbf);
  attn_mfma_kernel<<<dim3(BB*NN*2/MQ), 256, 0, stream>>>(Qbf, Kbf, Vbf, x, gamma, out);
}